// Round 1
// baseline (235.595 us; speedup 1.0000x reference)
//
#include <hip/hip_runtime.h>

#define DIM 64

// One block per match n. 256 threads = 16 groups of 16 lanes.
// Each group computes one length-64 dot product per iteration via float4
// loads (16 B/lane, 256 B coalesced per row) + shuffle reduction.
__global__ __launch_bounds__(256) void pixel_ap_main(
    const float* __restrict__ d1, const float* __restrict__ d2,
    const float* __restrict__ qw, const float* __restrict__ qb,
    const int* __restrict__ m1, const int* __restrict__ m2,
    const int* __restrict__ offs,
    float* __restrict__ partial, int P, int NEG, int NQ2)
{
    const int n   = blockIdx.x;
    const int tid = threadIdx.x;
    const int nq  = NQ2 >> 1;
    const int M   = NEG + 1;   // number of scores (pos + negatives)

    __shared__ float s_a1[DIM];
    __shared__ int   s_off[128];
    __shared__ float s_scores[1 + 128];
    __shared__ float s_nbs[32];
    __shared__ float s_rec[32];

    const int i1 = m1[n];
    const int i2 = m2[n];

    if (tid < DIM) s_a1[tid] = d1[(size_t)i1 * DIM + tid];
    if (tid >= 64 && tid - 64 < NEG) s_off[tid - 64] = offs[tid - 64];
    __syncthreads();

    const int g = tid >> 4;     // group 0..15
    const int l = tid & 15;     // lane within group
    const float4 a4 = ((const float4*)s_a1)[l];

    for (int j = g; j < M; j += 16) {
        int row = (j == 0) ? i2 : min(i2 + s_off[j - 1], P - 1);
        const float4 b4 = ((const float4*)(d2 + (size_t)row * DIM))[l];
        float s = a4.x * b4.x + a4.y * b4.y + a4.z * b4.z + a4.w * b4.w;
        s += __shfl_xor(s, 1);
        s += __shfl_xor(s, 2);
        s += __shfl_xor(s, 4);
        s += __shfl_xor(s, 8);
        if (l == 0) s_scores[j] = s;
    }
    __syncthreads();

    // Quantizer bins: thread k owns bin k.
    if (tid < nq) {
        const float wlo = qw[tid],      whi = qw[nq + tid];
        const float blo = qb[tid],      bhi = qb[nq + tid];
        float nbs = 0.f, rec = 0.f;
        for (int j = 0; j < M; ++j) {
            const float x = s_scores[j];
            float q = fminf(wlo * x + blo, whi * x + bhi);
            q = fmaxf(q, 0.f);
            nbs += q;
            if (j == 0) rec = q;
        }
        s_nbs[tid] = nbs;
        s_rec[tid] = rec;
    }
    __syncthreads();

    if (tid == 0) {
        float cr = 0.f, cn = 0.f, ap = 0.f, rsum = 0.f;
        for (int k = 0; k < nq; ++k) {
            const float r = s_rec[k];
            cr += r;
            cn += s_nbs[k];
            const float prec = cr / (1e-16f + cn);
            ap   += prec * r;
            rsum += r;
        }
        ap = ap / rsum;
        partial[n] = 1.0f - ap;
    }
}

__global__ __launch_bounds__(256) void pixel_ap_reduce(
    const float* __restrict__ partial, float* __restrict__ out, int N)
{
    float s = 0.f;
    for (int i = threadIdx.x; i < N; i += 256) s += partial[i];
    for (int off = 32; off >= 1; off >>= 1) s += __shfl_down(s, off);
    __shared__ float s_w[4];
    const int wid = threadIdx.x >> 6;
    if ((threadIdx.x & 63) == 0) s_w[wid] = s;
    __syncthreads();
    if (threadIdx.x == 0) {
        float t = s_w[0] + s_w[1] + s_w[2] + s_w[3];
        out[0] = t / (float)N;
    }
}

extern "C" void kernel_launch(void* const* d_in, const int* in_sizes, int n_in,
                              void* d_out, int out_size, void* d_ws, size_t ws_size,
                              hipStream_t stream) {
    const float* d1   = (const float*)d_in[0];
    const float* d2   = (const float*)d_in[1];
    const float* qw   = (const float*)d_in[2];
    const float* qb   = (const float*)d_in[3];
    const int*   m1   = (const int*)d_in[4];
    const int*   m2   = (const int*)d_in[5];
    const int*   offs = (const int*)d_in[6];

    const int N    = in_sizes[4];
    const int P    = in_sizes[0] / DIM;
    const int NEG  = in_sizes[6];
    const int NQ2  = in_sizes[2];

    float* partial = (float*)d_ws;

    pixel_ap_main<<<N, 256, 0, stream>>>(d1, d2, qw, qb, m1, m2, offs,
                                         partial, P, NEG, NQ2);
    pixel_ap_reduce<<<1, 256, 0, stream>>>(partial, (float*)d_out, N);
}

// Round 2
// 203.711 us; speedup vs baseline: 1.1565x; 1.1565x over previous
//
#include <hip/hip_runtime.h>

#define DIM 64

// ---------------- sort-by-m2 helper kernels ----------------

__global__ __launch_bounds__(256) void k_zero(int* __restrict__ cnt, int nbuck) {
    int i = blockIdx.x * 256 + threadIdx.x;
    if (i < nbuck) cnt[i] = 0;
}

__global__ __launch_bounds__(256) void k_hist(const int* __restrict__ m2,
                                              int* __restrict__ cnt, int N) {
    int n = blockIdx.x * 256 + threadIdx.x;
    if (n < N) atomicAdd(&cnt[m2[n] >> 7], 1);
}

// exclusive prefix over nbuck (<= 2560) counts, in place
__global__ __launch_bounds__(256) void k_scan(int* __restrict__ cnt, int nbuck) {
    __shared__ int s[256];
    const int tid = threadIdx.x;
    const int base = tid * 10;
    int loc[10];
    int sum = 0;
    #pragma unroll
    for (int i = 0; i < 10; ++i) {
        int idx = base + i;
        int v = (idx < nbuck) ? cnt[idx] : 0;
        loc[i] = sum;          // exclusive within chunk
        sum += v;
    }
    s[tid] = sum;
    __syncthreads();
    for (int off = 1; off < 256; off <<= 1) {
        int v = (tid >= off) ? s[tid - off] : 0;
        __syncthreads();
        s[tid] += v;
        __syncthreads();
    }
    const int excl = (tid > 0) ? s[tid - 1] : 0;
    #pragma unroll
    for (int i = 0; i < 10; ++i) {
        int idx = base + i;
        if (idx < nbuck) cnt[idx] = excl + loc[i];
    }
}

__global__ __launch_bounds__(256) void k_scatter(const int* __restrict__ m2,
                                                 int* __restrict__ cnt,
                                                 int* __restrict__ perm, int N) {
    int n = blockIdx.x * 256 + threadIdx.x;
    if (n < N) {
        int pos = atomicAdd(&cnt[m2[n] >> 7], 1);
        perm[pos] = n;
    }
}

// ---------------- main kernel: one block per match ----------------

__global__ __launch_bounds__(256) void pixel_ap_main(
    const float* __restrict__ d1, const float* __restrict__ d2,
    const float* __restrict__ qw, const float* __restrict__ qb,
    const int* __restrict__ m1, const int* __restrict__ m2,
    const int* __restrict__ offs, const int* __restrict__ perm,
    float* __restrict__ partial, int P, int NEG, int NQ2)
{
    const int tid = threadIdx.x;
    const int nq  = NQ2 >> 1;
    const int M   = NEG + 1;          // 81 scores

    __shared__ float s_a1[DIM];
    __shared__ int   s_off[128];
    __shared__ float s_scores[160];
    __shared__ float s_red[8];

    const int n  = perm[blockIdx.x];
    const int i1 = m1[n];
    const int i2 = m2[n];

    if (tid < DIM) s_a1[tid] = d1[(size_t)i1 * DIM + tid];
    if (tid >= 64 && tid < 64 + NEG) s_off[tid - 64] = offs[tid - 64];
    __syncthreads();

    const int g = tid >> 4;     // group 0..15, one score per iteration
    const int l = tid & 15;     // lane in group: 16 B each -> 256 B/row
    const float4 a4 = ((const float4*)s_a1)[l];

    // ---- gather + dot: unrolled so all loads issue before the reductions ----
    float4 bv[6];
    #pragma unroll
    for (int t = 0; t < 6; ++t) {
        const int j = g + 16 * t;
        if (j < M) {
            const int row = (j == 0) ? i2 : min(i2 + s_off[j - 1], P - 1);
            bv[t] = ((const float4*)(d2 + (size_t)row * DIM))[l];
        }
    }
    #pragma unroll
    for (int t = 0; t < 6; ++t) {
        const int j = g + 16 * t;
        if (j < M) {
            float s = bv[t].x * a4.x + bv[t].y * a4.y + bv[t].z * a4.z + bv[t].w * a4.w;
            s += __shfl_xor(s, 1);
            s += __shfl_xor(s, 2);
            s += __shfl_xor(s, 4);
            s += __shfl_xor(s, 8);
            if (l == 0) s_scores[j] = s;
        }
    }
    __syncthreads();

    // ---- hat-basis AP epilogue ----
    // u = a*(x-mn) clamped to [0, nq-1]; score -> (1-f)@i, f@(i+1).
    // ap = fp^2/(eps+N1) + (1-fp)/(eps+N2),
    //   N2 = sum_j [i_j >= ip] + sum_{i_j==ip-1} f_j   (suffix mass at ip)
    //   N1 = same at ip+1.
    const float a_scale = qw[nq];          // +a
    const float amn     = qb[nq - 1] - 1.0f; // a*mn
    const float ulim    = (float)(nq - 1);

    const float xp = s_scores[0];
    const float up = fminf(fmaxf(a_scale * xp - amn, 0.0f), ulim);
    const float ip = floorf(up);
    const float fp = up - ip;

    float n1 = 0.0f, n2 = 0.0f;
    if (tid < M) {
        const float x = s_scores[tid];
        const float u = fminf(fmaxf(a_scale * x - amn, 0.0f), ulim);
        const float fi = floorf(u);
        const float f  = u - fi;
        n2 = (fi >= ip)        ? 1.0f : ((fi == ip - 1.0f) ? f : 0.0f);
        n1 = (fi >= ip + 1.0f) ? 1.0f : ((fi == ip)        ? f : 0.0f);
    }
    #pragma unroll
    for (int off = 32; off >= 1; off >>= 1) {
        n1 += __shfl_down(n1, off);
        n2 += __shfl_down(n2, off);
    }
    const int wid = tid >> 6;
    if ((tid & 63) == 0) { s_red[wid] = n1; s_red[4 + wid] = n2; }
    __syncthreads();
    if (tid == 0) {
        const float N1 = s_red[0] + s_red[1] + s_red[2] + s_red[3];
        const float N2 = s_red[4] + s_red[5] + s_red[6] + s_red[7];
        const float ap = fp * fp / (1e-16f + N1) + (1.0f - fp) / (1e-16f + N2);
        partial[n] = 1.0f - ap;
    }
}

// ---------------- two-stage reduction ----------------

__global__ __launch_bounds__(256) void k_reduce1(const float* __restrict__ partial,
                                                 float* __restrict__ partial2, int N) {
    float s = 0.0f;
    for (int i = blockIdx.x * 256 + threadIdx.x; i < N; i += gridDim.x * 256) s += partial[i];
    #pragma unroll
    for (int off = 32; off >= 1; off >>= 1) s += __shfl_down(s, off);
    __shared__ float s_w[4];
    if ((threadIdx.x & 63) == 0) s_w[threadIdx.x >> 6] = s;
    __syncthreads();
    if (threadIdx.x == 0) partial2[blockIdx.x] = s_w[0] + s_w[1] + s_w[2] + s_w[3];
}

__global__ __launch_bounds__(64) void k_reduce2(const float* __restrict__ partial2,
                                                float* __restrict__ out, int nb, int N) {
    float s = 0.0f;
    for (int i = threadIdx.x; i < nb; i += 64) s += partial2[i];
    #pragma unroll
    for (int off = 32; off >= 1; off >>= 1) s += __shfl_down(s, off);
    if (threadIdx.x == 0) out[0] = s / (float)N;
}

extern "C" void kernel_launch(void* const* d_in, const int* in_sizes, int n_in,
                              void* d_out, int out_size, void* d_ws, size_t ws_size,
                              hipStream_t stream) {
    const float* d1   = (const float*)d_in[0];
    const float* d2   = (const float*)d_in[1];
    const float* qw   = (const float*)d_in[2];
    const float* qb   = (const float*)d_in[3];
    const int*   m1   = (const int*)d_in[4];
    const int*   m2   = (const int*)d_in[5];
    const int*   offs = (const int*)d_in[6];

    const int N    = in_sizes[4];
    const int P    = in_sizes[0] / DIM;
    const int NEG  = in_sizes[6];
    const int NQ2  = in_sizes[2];
    const int nbuck = (P + 127) >> 7;      // m2 >> 7 buckets

    int*   cnt      = (int*)d_ws;
    int*   perm     = cnt + nbuck;
    float* partial  = (float*)(perm + N);
    float* partial2 = partial + N;
    const int RB = 80;                     // reduce1 blocks

    const int nblk = (N + 255) / 256;

    k_zero   <<<(nbuck + 255) / 256, 256, 0, stream>>>(cnt, nbuck);
    k_hist   <<<nblk, 256, 0, stream>>>(m2, cnt, N);
    k_scan   <<<1, 256, 0, stream>>>(cnt, nbuck);
    k_scatter<<<nblk, 256, 0, stream>>>(m2, cnt, perm, N);

    pixel_ap_main<<<N, 256, 0, stream>>>(d1, d2, qw, qb, m1, m2, offs, perm,
                                         partial, P, NEG, NQ2);

    k_reduce1<<<RB, 256, 0, stream>>>(partial, partial2, N);
    k_reduce2<<<1, 64, 0, stream>>>(partial2, (float*)d_out, RB, N);
}